// Round 9
// baseline (255.826 us; speedup 1.0000x reference)
//
#include <hip/hip_runtime.h>
#include <stdint.h>

// ---------------- problem constants ----------------
#define BATCH 32
#define ICH 128
#define OCH 128
#define KBR 4
#define HH 64
#define WW 64
#define TAPS 25   // 5x5
// conv kernel tiling
#define XROWS 8    // staged input rows (4 out rows + 2 halo each side)
#define XCOLS 68   // staged input cols (-2..65)
#define XCP 40     // channel dim padded 32 -> 40 (80B rows: 2-way-conflict-free)
#define WROWP 40   // W panel row padded 32 -> 40

typedef __bf16 bf16x8 __attribute__((ext_vector_type(8)));
typedef float f32x4 __attribute__((ext_vector_type(4)));

static __device__ __forceinline__ ushort f2bf(float f) {
    union { float f; uint32_t u; } v; v.f = f;
    uint32_t u = v.u;
    uint32_t r = (u + 0x7FFFu + ((u >> 16) & 1u)) >> 16;
    return (ushort)r;
}
static __device__ __forceinline__ float bf2f(ushort s) {
    union { uint32_t u; float f; } v; v.u = ((uint32_t)s) << 16;
    return v.f;
}

// ---------------------------------------------------------------------------
// K3: NCHW fp32 -> NHWC bf16 transpose, plus per-(b,y) channel pooling partials
// grid: (BATCH*HH) blocks of 256
// ---------------------------------------------------------------------------
__global__ __launch_bounds__(256) void k_prep(const float* __restrict__ x,
                                              ushort* __restrict__ xT,
                                              float* __restrict__ partial) {
    int blk = blockIdx.x;
    int b = blk >> 6, y = blk & 63;
    __shared__ __align__(16) ushort tile[64][130];  // [x][ch], 260B row stride -> conflict-free
    const float* src = x + ((size_t)b * ICH) * (HH * WW) + (size_t)y * WW;
    int tid = threadIdx.x;
#pragma unroll
    for (int j = 0; j < 32; ++j) {
        int e = tid + 256 * j;          // e = i*64 + xc
        int i = e >> 6, xc = e & 63;
        float v = src[(size_t)i * (HH * WW) + xc];
        tile[xc][i] = f2bf(v);
    }
    __syncthreads();
    // write NHWC bf16, 2 ushorts per store
    uint* dst = (uint*)(xT + (((size_t)b * HH + y) * WW) * ICH);
#pragma unroll
    for (int j = 0; j < 16; ++j) {
        int p = tid + 256 * j;          // pair index: xc*64 + i/2
        int xc = p >> 6, ih = (p & 63) * 2;
        uint v = (uint)tile[xc][ih] | ((uint)tile[xc][ih + 1] << 16);
        dst[p] = v;
    }
    // pooling partial: sum over x for each channel (this row)
    if (tid < 128) {
        float s = 0.f;
        for (int xc = 0; xc < 64; ++xc) s += bf2f(tile[xc][tid]);
        partial[((size_t)b * HH + y) * ICH + tid] = s;
    }
}

// ---------------------------------------------------------------------------
// K1: finish pooling, dense->relu->dense->softmax, bias_eff
// grid: BATCH blocks of 128
// ---------------------------------------------------------------------------
__global__ __launch_bounds__(128) void k_attn(const float* __restrict__ partial,
                                              const float* __restrict__ a1_w,
                                              const float* __restrict__ a1_b,
                                              const float* __restrict__ a2_w,
                                              const float* __restrict__ a2_b,
                                              const float* __restrict__ bias,
                                              float* __restrict__ attn,
                                              float* __restrict__ bias_eff) {
    int b = blockIdx.x;
    int t = threadIdx.x;
    __shared__ float pl[128], hh[128], lg[4], at[4];
    {
        float s = 0.f;
        const float* p = partial + (size_t)b * 64 * 128 + t;
        for (int y = 0; y < 64; ++y) s += p[y * 128];
        pl[t] = s * (1.f / 4096.f);
    }
    __syncthreads();
    {
        float a = a1_b[t];
        const float* w1 = a1_w + t * 128;
        for (int i = 0; i < 128; ++i) a += pl[i] * w1[i];
        hh[t] = a > 0.f ? a : 0.f;
    }
    __syncthreads();
    if (t < 4) {
        float l = a2_b[t];
        const float* w2 = a2_w + t * 128;
        for (int i = 0; i < 128; ++i) l += hh[i] * w2[i];
        lg[t] = l;
    }
    __syncthreads();
    if (t == 0) {
        float m = fmaxf(fmaxf(lg[0], lg[1]), fmaxf(lg[2], lg[3]));
        float e0 = expf(lg[0] - m), e1 = expf(lg[1] - m);
        float e2 = expf(lg[2] - m), e3 = expf(lg[3] - m);
        float inv = 1.f / (e0 + e1 + e2 + e3);
        at[0] = e0 * inv; at[1] = e1 * inv; at[2] = e2 * inv; at[3] = e3 * inv;
        attn[b * 4 + 0] = at[0]; attn[b * 4 + 1] = at[1];
        attn[b * 4 + 2] = at[2]; attn[b * 4 + 3] = at[3];
    }
    __syncthreads();
    bias_eff[b * 128 + t] = at[0] * bias[0 * 128 + t] + at[1] * bias[1 * 128 + t] +
                            at[2] * bias[2 * 128 + t] + at[3] * bias[3 * 128 + t];
}

// ---------------------------------------------------------------------------
// K2: W_eff[b][o][tap][ch] bf16 = sum_k attn[b][k] * weight[k][o][ch][tap]
// grid: BATCH*OCH blocks of 256
// ---------------------------------------------------------------------------
__global__ __launch_bounds__(256) void k_wcomb(const float* __restrict__ weight,
                                               const float* __restrict__ attn,
                                               ushort* __restrict__ Weff) {
    int blk = blockIdx.x;
    int b = blk >> 7, o = blk & 127;
    float a0 = attn[b * 4 + 0], a1 = attn[b * 4 + 1];
    float a2 = attn[b * 4 + 2], a3 = attn[b * 4 + 3];
    __shared__ float wt[3200];   // [ch][tap] as in source layout
    const float* w = weight + (size_t)o * 3200;   // k-stride = 128*3200 = 409600
    for (int e = threadIdx.x; e < 3200; e += 256) {
        wt[e] = a0 * w[e] + a1 * w[409600 + e] + a2 * w[819200 + e] + a3 * w[1228800 + e];
    }
    __syncthreads();
    ushort* dst = Weff + ((size_t)(b * 128 + o)) * 3200;
    for (int f = threadIdx.x; f < 3200; f += 256) {
        int t = f >> 7, i = f & 127;   // out: tap-major, channel-inner
        dst[f] = f2bf(wt[i * 25 + t]);
    }
}

// ---------------------------------------------------------------------------
// K4: per-sample conv as implicit GEMM.
// Block: 512 thr (8 waves, 2Mx4N), out tile = 128 O x 256 px (4 rows).
// K-loop: 4 channel-chunks of 32 x 25 taps; x-slice + per-tap W panel in LDS.
// grid: BATCH * 16 blocks
// ---------------------------------------------------------------------------
__global__ __launch_bounds__(512) void k_conv(const ushort* __restrict__ xT,
                                              const ushort* __restrict__ Weff,
                                              const float* __restrict__ bias_eff,
                                              float* __restrict__ out) {
    __shared__ __align__(16) ushort lx[XROWS * XCOLS * XCP];  // 43,520 B
    __shared__ __align__(16) ushort lw[128 * WROWP];          // 10,240 B

    int blk = blockIdx.x;
    int b = blk >> 4, rg = blk & 15;
    int y0 = rg * 4;
    int tid = threadIdx.x;
    int lane = tid & 63, wid = tid >> 6;
    int wm = wid >> 2, wn = wid & 3;
    int row16 = lane & 15, kg = lane >> 4;

    f32x4 acc[4][4];
    f32x4 zero = {0.f, 0.f, 0.f, 0.f};
#pragma unroll
    for (int m = 0; m < 4; ++m)
#pragma unroll
        for (int n = 0; n < 4; ++n) acc[m][n] = zero;

    const ushort* xb = xT + ((size_t)b * HH * WW) * ICH;
    const ushort* wb = Weff + ((size_t)b * OCH) * 3200;

    for (int ic = 0; ic < 128; ic += 32) {
        __syncthreads();   // prev tap's compute done reading lx
        // ---- stage x slice: rows y0-2..y0+5, cols -2..65, ch ic..ic+31 ----
        for (int q = tid; q < XROWS * XCOLS * 4; q += 512) {
            int s = q / (XCOLS * 4);
            int rem = q - s * (XCOLS * 4);
            int c = rem >> 2, part = rem & 3;
            int gy = y0 - 2 + s, gx = c - 2;
            uint4 val = make_uint4(0u, 0u, 0u, 0u);
            if (gy >= 0 && gy < 64 && gx >= 0 && gx < 64) {
                val = *(const uint4*)(xb + ((size_t)(gy * 64 + gx)) * ICH + ic + part * 8);
            }
            *(uint4*)(&lx[(s * XCOLS + c) * XCP + part * 8]) = val;
        }
        for (int t = 0; t < TAPS; ++t) {
            __syncthreads();   // x staged / prev compute done reading lw
            // ---- stage W panel: [128 o][32 ch] at tap t ----
            {
                int o = tid >> 2, part = tid & 3;
                uint4 wv = *(const uint4*)(wb + ((size_t)o * 25 + t) * 128 + ic + part * 8);
                *(uint4*)(&lw[o * WROWP + part * 8]) = wv;
            }
            __syncthreads();
            int kh = t / 5, kw = t - kh * 5;
            bf16x8 af[4], bfr[4];
#pragma unroll
            for (int m = 0; m < 4; ++m) {
                int o = wm * 64 + m * 16 + row16;
                af[m] = *(const bf16x8*)(&lw[o * WROWP + kg * 8]);
            }
#pragma unroll
            for (int n = 0; n < 4; ++n) {
                int px = wn * 64 + n * 16 + row16;
                int yl = px >> 6, xc = px & 63;
                int s = yl + kh, cc = xc + kw;
                bfr[n] = *(const bf16x8*)(&lx[(s * XCOLS + cc) * XCP + kg * 8]);
            }
#pragma unroll
            for (int m = 0; m < 4; ++m)
#pragma unroll
                for (int n = 0; n < 4; ++n)
                    acc[m][n] = __builtin_amdgcn_mfma_f32_16x16x32_bf16(af[m], bfr[n], acc[m][n], 0, 0, 0);
        }
    }

    // ---- epilogue: add bias_eff, store fp32 NCHW ----
    float* ob = out + ((size_t)b * OCH) * (HH * WW);
#pragma unroll
    for (int m = 0; m < 4; ++m) {
#pragma unroll
        for (int r = 0; r < 4; ++r) {
            int o = wm * 64 + m * 16 + kg * 4 + r;
            float be = bias_eff[b * 128 + o];
#pragma unroll
            for (int n = 0; n < 4; ++n) {
                int px = wn * 64 + n * 16 + row16;
                int y = y0 + (px >> 6), xc = px & 63;
                ob[((size_t)o * 64 + y) * 64 + xc] = acc[m][n][r] + be;
            }
        }
    }
}

// ---------------------------------------------------------------------------
extern "C" void kernel_launch(void* const* d_in, const int* in_sizes, int n_in,
                              void* d_out, int out_size, void* d_ws, size_t ws_size,
                              hipStream_t stream) {
    const float* x      = (const float*)d_in[0];
    const float* weight = (const float*)d_in[1];
    const float* bias   = (const float*)d_in[2];
    const float* a1_w   = (const float*)d_in[3];
    const float* a1_b   = (const float*)d_in[4];
    const float* a2_w   = (const float*)d_in[5];
    const float* a2_b   = (const float*)d_in[6];
    float* out = (float*)d_out;

    // ws layout (bytes):
    //   xT      : 0          .. 33,554,432   (32*64*64*128 bf16)
    //   Weff    : 33,554,432 .. 59,768,832   (32*128*25*128 bf16)
    //   partial : 59,768,832 .. 60,817,408   (32*64*128 f32)
    //   attn    : 60,817,408 .. 60,817,920   (32*4 f32)
    //   bias_eff: 60,817,920 .. 60,834,304   (32*128 f32)
    const size_t WS_REQUIRED = 60834304;
    // Defensive: if the harness workspace is smaller than our layout, launching
    // would fault the GPU (container-killing). Skip instead -> clean absmax
    // failure that diagnoses ws_size as the problem. Deterministic per call.
    if (ws_size < WS_REQUIRED) return;

    char* ws = (char*)d_ws;
    ushort* xT       = (ushort*)(ws);
    ushort* Weff     = (ushort*)(ws + 33554432);
    float*  partial  = (float*)(ws + 59768832);
    float*  attn     = (float*)(ws + 60817408);
    float*  bias_eff = (float*)(ws + 60817920);

    k_prep<<<dim3(BATCH * HH), dim3(256), 0, stream>>>(x, xT, partial);
    k_attn<<<dim3(BATCH), dim3(128), 0, stream>>>(partial, a1_w, a1_b, a2_w, a2_b, bias,
                                                  attn, bias_eff);
    k_wcomb<<<dim3(BATCH * OCH), dim3(256), 0, stream>>>(weight, attn, Weff);
    k_conv<<<dim3(BATCH * 16), dim3(512), 0, stream>>>(xT, Weff, bias_eff, out);
}

// Round 11
// 241.210 us; speedup vs baseline: 1.0606x; 1.0606x over previous
//
#include <hip/hip_runtime.h>
#include <stdint.h>

// ---------------- problem constants ----------------
#define BATCH 32
#define ICH 128
#define OCH 128
#define KBR 4
#define HH 64
#define WW 64
#define TAPS 25   // 5x5
// conv kernel tiling
#define XROWS 8    // staged input rows (4 out rows + 2 halo each side)
#define XCOLS 68   // staged input cols (-2..65)
#define XCP 40     // channel dim padded 32 -> 40 (80B rows: 2-way-conflict-free)
#define WROWP 40   // W panel row padded 32 -> 40

typedef __bf16 bf16x8 __attribute__((ext_vector_type(8)));
typedef float f32x4 __attribute__((ext_vector_type(4)));

static __device__ __forceinline__ ushort f2bf(float f) {
    union { float f; uint32_t u; } v; v.f = f;
    uint32_t u = v.u;
    uint32_t r = (u + 0x7FFFu + ((u >> 16) & 1u)) >> 16;
    return (ushort)r;
}
static __device__ __forceinline__ float bf2f(ushort s) {
    union { uint32_t u; float f; } v; v.u = ((uint32_t)s) << 16;
    return v.f;
}

// ---------------------------------------------------------------------------
// K3: NCHW fp32 -> NHWC bf16 transpose, plus per-(b,y) channel pooling partials
// grid: (BATCH*HH) blocks of 256
// ---------------------------------------------------------------------------
__global__ __launch_bounds__(256) void k_prep(const float* __restrict__ x,
                                              ushort* __restrict__ xT,
                                              float* __restrict__ partial) {
    int blk = blockIdx.x;
    int b = blk >> 6, y = blk & 63;
    __shared__ __align__(16) ushort tile[64][130];  // [x][ch], 260B row stride -> conflict-free
    const float* src = x + ((size_t)b * ICH) * (HH * WW) + (size_t)y * WW;
    int tid = threadIdx.x;
    // float4 loads: wave reads 1KB/instr (G13)
#pragma unroll
    for (int j = 0; j < 8; ++j) {
        int e = (tid + 256 * j) * 4;    // e = i*64 + xc, xc multiple of 4
        int i = e >> 6, xc = e & 63;
        float4 v = *(const float4*)(src + (size_t)i * (HH * WW) + xc);
        tile[xc + 0][i] = f2bf(v.x);
        tile[xc + 1][i] = f2bf(v.y);
        tile[xc + 2][i] = f2bf(v.z);
        tile[xc + 3][i] = f2bf(v.w);
    }
    __syncthreads();
    // write NHWC bf16, 2 ushorts per store
    uint* dst = (uint*)(xT + (((size_t)b * HH + y) * WW) * ICH);
#pragma unroll
    for (int j = 0; j < 16; ++j) {
        int p = tid + 256 * j;          // pair index: xc*64 + i/2
        int xc = p >> 6, ih = (p & 63) * 2;
        uint v = (uint)tile[xc][ih] | ((uint)tile[xc][ih + 1] << 16);
        dst[p] = v;
    }
    // pooling partial: sum over x for each channel (this row)
    if (tid < 128) {
        float s = 0.f;
        for (int xc = 0; xc < 64; ++xc) s += bf2f(tile[xc][tid]);
        partial[((size_t)b * HH + y) * ICH + tid] = s;
    }
}

// ---------------------------------------------------------------------------
// K1: finish pooling, dense->relu->dense->softmax, bias_eff
// grid: BATCH blocks of 128
// ---------------------------------------------------------------------------
__global__ __launch_bounds__(128) void k_attn(const float* __restrict__ partial,
                                              const float* __restrict__ a1_w,
                                              const float* __restrict__ a1_b,
                                              const float* __restrict__ a2_w,
                                              const float* __restrict__ a2_b,
                                              const float* __restrict__ bias,
                                              float* __restrict__ attn,
                                              float* __restrict__ bias_eff) {
    int b = blockIdx.x;
    int t = threadIdx.x;
    __shared__ float pl[128], hh[128], lg[4], at[4];
    {
        float s = 0.f;
        const float* p = partial + (size_t)b * 64 * 128 + t;
        for (int y = 0; y < 64; ++y) s += p[y * 128];
        pl[t] = s * (1.f / 4096.f);
    }
    __syncthreads();
    {
        float a = a1_b[t];
        const float* w1 = a1_w + t * 128;
        for (int i = 0; i < 128; ++i) a += pl[i] * w1[i];
        hh[t] = a > 0.f ? a : 0.f;
    }
    __syncthreads();
    if (t < 4) {
        float l = a2_b[t];
        const float* w2 = a2_w + t * 128;
        for (int i = 0; i < 128; ++i) l += hh[i] * w2[i];
        lg[t] = l;
    }
    __syncthreads();
    if (t == 0) {
        float m = fmaxf(fmaxf(lg[0], lg[1]), fmaxf(lg[2], lg[3]));
        float e0 = expf(lg[0] - m), e1 = expf(lg[1] - m);
        float e2 = expf(lg[2] - m), e3 = expf(lg[3] - m);
        float inv = 1.f / (e0 + e1 + e2 + e3);
        at[0] = e0 * inv; at[1] = e1 * inv; at[2] = e2 * inv; at[3] = e3 * inv;
        attn[b * 4 + 0] = at[0]; attn[b * 4 + 1] = at[1];
        attn[b * 4 + 2] = at[2]; attn[b * 4 + 3] = at[3];
    }
    __syncthreads();
    bias_eff[b * 128 + t] = at[0] * bias[0 * 128 + t] + at[1] * bias[1 * 128 + t] +
                            at[2] * bias[2 * 128 + t] + at[3] * bias[3 * 128 + t];
}

// ---------------------------------------------------------------------------
// K2: W_eff[b][o][tap][ch] bf16 = sum_k attn[b][k] * weight[k][o][ch][tap]
// grid: BATCH*OCH blocks of 256
// ---------------------------------------------------------------------------
__global__ __launch_bounds__(256) void k_wcomb(const float* __restrict__ weight,
                                               const float* __restrict__ attn,
                                               ushort* __restrict__ Weff) {
    int blk = blockIdx.x;
    int b = blk >> 7, o = blk & 127;
    float a0 = attn[b * 4 + 0], a1 = attn[b * 4 + 1];
    float a2 = attn[b * 4 + 2], a3 = attn[b * 4 + 3];
    __shared__ float wt[3200];   // [ch][tap] as in source layout
    const float* w = weight + (size_t)o * 3200;   // k-stride = 128*3200 = 409600
    for (int e = threadIdx.x; e < 3200; e += 256) {
        wt[e] = a0 * w[e] + a1 * w[409600 + e] + a2 * w[819200 + e] + a3 * w[1228800 + e];
    }
    __syncthreads();
    ushort* dst = Weff + ((size_t)(b * 128 + o)) * 3200;
    for (int f = threadIdx.x; f < 3200; f += 256) {
        int t = f >> 7, i = f & 127;   // out: tap-major, channel-inner
        dst[f] = f2bf(wt[i * 25 + t]);
    }
}

// ---------------------------------------------------------------------------
// K4: per-sample conv as implicit GEMM.
// Block: 512 thr (8 waves, 2Mx4N), out tile = 128 O x 256 px (4 rows).
// Unified g-loop over 100 (ic-chunk, tap) steps; lw double-buffered with
// issue-early/write-late W staging (T14); lx restaged at 3 chunk boundaries.
// XCD-aware block mapping: each XCD owns 4 whole batch-samples (T1).
// grid: BATCH * 16 blocks
// ---------------------------------------------------------------------------
__global__ __launch_bounds__(512) void k_conv(const ushort* __restrict__ xT,
                                              const ushort* __restrict__ Weff,
                                              const float* __restrict__ bias_eff,
                                              float* __restrict__ out) {
    __shared__ __align__(16) ushort lx[XROWS * XCOLS * XCP];  // 43,520 B
    __shared__ __align__(16) ushort lw[2][128 * WROWP];       // 20,480 B (total 64,000 B)

    // T1: dispatch round-robins blockIdx across 8 XCDs (xcd = blk & 7).
    // Map so each XCD gets 4 whole samples -> Weff[b]/xT[b] hit ONE L2.
    int blk = blockIdx.x;
    int xcd = blk & 7, slot = blk >> 3;        // slot in [0,64)
    int b = xcd * 4 + (slot >> 4);
    int rg = slot & 15;
    int y0 = rg * 4;
    int tid = threadIdx.x;
    int lane = tid & 63, wid = tid >> 6;
    int wm = wid >> 2, wn = wid & 3;
    int row16 = lane & 15, kg = lane >> 4;

    f32x4 acc[4][4];
    f32x4 zero = {0.f, 0.f, 0.f, 0.f};
#pragma unroll
    for (int m = 0; m < 4; ++m)
#pragma unroll
        for (int n = 0; n < 4; ++n) acc[m][n] = zero;

    const ushort* xb = xT + ((size_t)b * HH * WW) * ICH;
    const ushort* wb = Weff + ((size_t)b * OCH) * 3200;

    int wo = tid >> 2, wpart = tid & 3;   // W-staging role of this thread

    // ---- prologue: stage lx(ic=0) and lw[0] = (ic=0, tap=0) ----
    {
        for (int q = tid; q < XROWS * XCOLS * 4; q += 512) {
            int s = q / (XCOLS * 4);
            int rem = q - s * (XCOLS * 4);
            int c = rem >> 2, part = rem & 3;
            int gy = y0 - 2 + s, gx = c - 2;
            uint4 val = make_uint4(0u, 0u, 0u, 0u);
            if (gy >= 0 && gy < 64 && gx >= 0 && gx < 64)
                val = *(const uint4*)(xb + ((size_t)(gy * 64 + gx)) * ICH + 0 + part * 8);
            *(uint4*)(&lx[(s * XCOLS + c) * XCP + part * 8]) = val;
        }
        uint4 wv = *(const uint4*)(wb + ((size_t)wo * 25 + 0) * 128 + 0 + wpart * 8);
        *(uint4*)(&lw[0][wo * WROWP + wpart * 8]) = wv;
    }
    __syncthreads();

    // ---- main loop: g = ic_chunk*25 + tap ----
    for (int g = 0; g < 100; ++g) {
        int buf = g & 1;
        int t = g % 25;
        // T14 issue-early: load next W panel to regs before compute
        uint4 wv;
        bool have_next = (g + 1 < 100);
        if (have_next) {
            int gn = g + 1;
            int icn = (gn / 25) * 32, tn = gn % 25;
            wv = *(const uint4*)(wb + ((size_t)wo * 25 + tn) * 128 + icn + wpart * 8);
        }
        // compute tap g
        {
            int kh = t / 5, kw = t - kh * 5;
            bf16x8 af[4], bfr[4];
#pragma unroll
            for (int m = 0; m < 4; ++m) {
                int o = wm * 64 + m * 16 + row16;
                af[m] = *(const bf16x8*)(&lw[buf][o * WROWP + kg * 8]);
            }
#pragma unroll
            for (int n = 0; n < 4; ++n) {
                int px = wn * 64 + n * 16 + row16;
                int yl = px >> 6, xc = px & 63;
                int s = yl + kh, cc = xc + kw;
                bfr[n] = *(const bf16x8*)(&lx[(s * XCOLS + cc) * XCP + kg * 8]);
            }
#pragma unroll
            for (int m = 0; m < 4; ++m)
#pragma unroll
                for (int n = 0; n < 4; ++n)
                    acc[m][n] = __builtin_amdgcn_mfma_f32_16x16x32_bf16(af[m], bfr[n], acc[m][n], 0, 0, 0);
        }
        // T14 write-late: commit next W panel to the alternate buffer
        if (have_next) {
            *(uint4*)(&lw[buf ^ 1][wo * WROWP + wpart * 8]) = wv;
        }
        if (t == 24) {
            // ic-chunk boundary: all lx reads done -> restage lx
            __syncthreads();
            if (g < 99) {
                int icn = ((g + 1) / 25) * 32;
                for (int q = tid; q < XROWS * XCOLS * 4; q += 512) {
                    int s = q / (XCOLS * 4);
                    int rem = q - s * (XCOLS * 4);
                    int c = rem >> 2, part = rem & 3;
                    int gy = y0 - 2 + s, gx = c - 2;
                    uint4 val = make_uint4(0u, 0u, 0u, 0u);
                    if (gy >= 0 && gy < 64 && gx >= 0 && gx < 64)
                        val = *(const uint4*)(xb + ((size_t)(gy * 64 + gx)) * ICH + icn + part * 8);
                    *(uint4*)(&lx[(s * XCOLS + c) * XCP + part * 8]) = val;
                }
            }
            __syncthreads();
        } else {
            __syncthreads();   // lw[buf^1] staged & visible for next tap
        }
    }

    // ---- epilogue: add bias_eff, store fp32 NCHW ----
    float* ob = out + ((size_t)b * OCH) * (HH * WW);
#pragma unroll
    for (int m = 0; m < 4; ++m) {
#pragma unroll
        for (int r = 0; r < 4; ++r) {
            int o = wm * 64 + m * 16 + kg * 4 + r;
            float be = bias_eff[b * 128 + o];
#pragma unroll
            for (int n = 0; n < 4; ++n) {
                int px = wn * 64 + n * 16 + row16;
                int y = y0 + (px >> 6), xc = px & 63;
                ob[((size_t)o * 64 + y) * 64 + xc] = acc[m][n][r] + be;
            }
        }
    }
}

// ---------------------------------------------------------------------------
extern "C" void kernel_launch(void* const* d_in, const int* in_sizes, int n_in,
                              void* d_out, int out_size, void* d_ws, size_t ws_size,
                              hipStream_t stream) {
    const float* x      = (const float*)d_in[0];
    const float* weight = (const float*)d_in[1];
    const float* bias   = (const float*)d_in[2];
    const float* a1_w   = (const float*)d_in[3];
    const float* a1_b   = (const float*)d_in[4];
    const float* a2_w   = (const float*)d_in[5];
    const float* a2_b   = (const float*)d_in[6];
    float* out = (float*)d_out;

    // ws layout (bytes):
    //   xT      : 0          .. 33,554,432   (32*64*64*128 bf16)
    //   Weff    : 33,554,432 .. 59,768,832   (32*128*25*128 bf16)
    //   partial : 59,768,832 .. 60,817,408   (32*64*128 f32)
    //   attn    : 60,817,408 .. 60,817,920   (32*4 f32)
    //   bias_eff: 60,817,920 .. 60,834,304   (32*128 f32)
    const size_t WS_REQUIRED = 60834304;
    if (ws_size < WS_REQUIRED) return;   // defensive: avoid OOB fault

    char* ws = (char*)d_ws;
    ushort* xT       = (ushort*)(ws);
    ushort* Weff     = (ushort*)(ws + 33554432);
    float*  partial  = (float*)(ws + 59768832);
    float*  attn     = (float*)(ws + 60817408);
    float*  bias_eff = (float*)(ws + 60817920);

    k_prep<<<dim3(BATCH * HH), dim3(256), 0, stream>>>(x, xT, partial);
    k_attn<<<dim3(BATCH), dim3(128), 0, stream>>>(partial, a1_w, a1_b, a2_w, a2_b, bias,
                                                  attn, bias_eff);
    k_wcomb<<<dim3(BATCH * OCH), dim3(256), 0, stream>>>(weight, attn, Weff);
    k_conv<<<dim3(BATCH * 16), dim3(512), 0, stream>>>(xT, Weff, bias_eff, out);
}